// Round 1
// baseline (37.341 us; speedup 1.0000x reference)
//
#include <hip/hip_runtime.h>
#include <math.h>

// Problem constants (from reference setup)
#define BATCH   8
#define NPTS    1024
#define MCTX    1024
#define BN      (BATCH * NPTS)     // 8192 rows, one wave each

// FEATURES_RANGE = [50, 50, 32, 32, pi]; feature 4 is cyclic
#define INV_R0  0.02f
#define INV_R1  0.02f
#define INV_R2  0.03125f
#define INV_R3  0.03125f
#define INV_R4  0.3183098861837907f   // 1/pi
#define MAX_DIST 50.0f

__global__ __launch_bounds__(256) void sim_kernel(
    const float* __restrict__ points,          // [B,N,5]
    const float* __restrict__ ctx,             // [B,M,5]
    const float* __restrict__ dist,            // [B,N,M]
    const unsigned char* __restrict__ imask,   // [B,N,M] bool as u8
    const int* __restrict__ gmd_p,             // scalar
    const float* __restrict__ W1p,             // [5,4] row-major
    const float* __restrict__ b1p,             // [4]
    const float* __restrict__ W2p,             // [4,1]
    const float* __restrict__ b2p,             // [1]
    const float* __restrict__ Wap,             // [5,1]
    const float* __restrict__ bap,             // [1]
    float* __restrict__ out)                   // [B,N]
{
    const int tid  = blockIdx.x * blockDim.x + threadIdx.x;
    const int row  = tid >> 6;                 // wave index = (b*N + n)
    const int lane = threadIdx.x & 63;
    if (row >= BN) return;
    const int b = row >> 10;

    // --- tiny weights into registers (broadcast loads, L2-hit) ---
    float w1[20];
#pragma unroll
    for (int i = 0; i < 20; ++i) w1[i] = W1p[i];
    float b1v[4];
#pragma unroll
    for (int j = 0; j < 4; ++j) b1v[j] = b1p[j];
    float w2[4];
#pragma unroll
    for (int j = 0; j < 4; ++j) w2[j] = W2p[j];
    const float b2v = b2p[0];
    float wa[5];
#pragma unroll
    for (int f = 0; f < 5; ++f) wa[f] = Wap[f];
    const float bav = bap[0];

    // --- this row's point features ---
    float p0 = points[row * 5 + 0];
    float p1 = points[row * 5 + 1];
    float p2 = points[row * 5 + 2];
    float p3 = points[row * 5 + 3];
    float p4 = points[row * 5 + 4];

    const bool tighten = (MAX_DIST < (float)gmd_p[0]);
    const float* __restrict__ drow        = dist  + (size_t)row * MCTX;
    const unsigned char* __restrict__ mrow = imask + (size_t)row * MCTX;
    const float* __restrict__ cb          = ctx   + (size_t)b * MCTX * 5;

    // online softmax state
    float mrun = -1e30f, lrun = 0.0f, acc = 0.0f;

    for (int m = lane; m < MCTX; m += 64) {
        bool ib = (mrow[m] != 0);
        float d = drow[m];
        if (tighten) ib = ib && (d <= MAX_DIST);
        if (!ib) continue;

        const float* c = cb + m * 5;
        float fn0 = fabsf(p0 - c[0]) * INV_R0;
        float fn1 = fabsf(p1 - c[1]) * INV_R1;
        float fn2 = fabsf(p2 - c[2]) * INV_R2;
        float fn3 = fabsf(p3 - c[3]) * INV_R3;
        float f4  = fabsf(p4 - c[4]) * INV_R4;
        f4 = f4 - floorf(f4);                  // remainder(x,1) for x>=0
        float fn4 = fminf(f4, 1.0f - f4);      // cyclic wrap distance

        // MLP: h = relu(fn @ W1 + b1)   (W1 is [5,4] row-major: W1[f*4+j])
        float h0 = fmaxf(0.0f, b1v[0] + fn0*w1[0]  + fn1*w1[4]  + fn2*w1[8]  + fn3*w1[12] + fn4*w1[16]);
        float h1 = fmaxf(0.0f, b1v[1] + fn0*w1[1]  + fn1*w1[5]  + fn2*w1[9]  + fn3*w1[13] + fn4*w1[17]);
        float h2 = fmaxf(0.0f, b1v[2] + fn0*w1[2]  + fn1*w1[6]  + fn2*w1[10] + fn3*w1[14] + fn4*w1[18]);
        float h3 = fmaxf(0.0f, b1v[3] + fn0*w1[3]  + fn1*w1[7]  + fn2*w1[11] + fn3*w1[15] + fn4*w1[19]);
        float z  = b2v + h0*w2[0] + h1*w2[1] + h2*w2[2] + h3*w2[3];
        float energy = 1.0f / (1.0f + __expf(-z));       // sigmoid

        float score = bav + fn0*wa[0] + fn1*wa[1] + fn2*wa[2] + fn3*wa[3] + fn4*wa[4];

        // online softmax accumulate
        if (score > mrun) {
            float sc = __expf(mrun - score);
            lrun *= sc; acc *= sc; mrun = score;
        }
        float e = __expf(score - mrun);
        lrun += e;
        acc  += e * energy;
    }

    // --- 64-lane butterfly merge of (m, l, acc) ---
#pragma unroll
    for (int off = 1; off < 64; off <<= 1) {
        float m2 = __shfl_xor(mrun, off, 64);
        float l2 = __shfl_xor(lrun, off, 64);
        float a2 = __shfl_xor(acc,  off, 64);
        float mn = fmaxf(mrun, m2);
        float s1 = __expf(mrun - mn);
        float s2 = __expf(m2   - mn);
        lrun = lrun * s1 + l2 * s2;
        acc  = acc  * s1 + a2 * s2;
        mrun = mn;
    }

    if (lane == 0) {
        out[row] = (lrun > 0.0f) ? (acc / lrun) : 0.0f;   // all-masked -> 0
    }
}

extern "C" void kernel_launch(void* const* d_in, const int* in_sizes, int n_in,
                              void* d_out, int out_size, void* d_ws, size_t ws_size,
                              hipStream_t stream) {
    const float*         points = (const float*)d_in[0];
    // d_in[1] points_mask: unused by reference
    const float*         ctx    = (const float*)d_in[2];
    // d_in[3] context_points_mask: unused by reference
    const float*         dist   = (const float*)d_in[4];
    const unsigned char* imask  = (const unsigned char*)d_in[5];
    const int*           gmd    = (const int*)d_in[6];
    const float*         W1     = (const float*)d_in[7];
    const float*         b1     = (const float*)d_in[8];
    const float*         W2     = (const float*)d_in[9];
    const float*         b2     = (const float*)d_in[10];
    const float*         Wa     = (const float*)d_in[11];
    const float*         ba     = (const float*)d_in[12];
    float*               out    = (float*)d_out;

    // one 64-lane wave per (b,n) row; 4 waves per 256-thread block
    dim3 block(256);
    dim3 grid(BN / 4);   // 2048 blocks
    sim_kernel<<<grid, block, 0, stream>>>(points, ctx, dist, imask, gmd,
                                           W1, b1, W2, b2, Wa, ba, out);
}

// Round 2
// 28.273 us; speedup vs baseline: 1.3207x; 1.3207x over previous
//
#include <hip/hip_runtime.h>
#include <math.h>

// Problem constants (from reference setup)
#define BATCH   8
#define NPTS    1024
#define MCTX    1024
#define BN      (BATCH * NPTS)     // 8192 rows, one wave each

// FEATURES_RANGE = [50, 50, 32, 32, pi]; feature 4 is cyclic
#define INV_R0  0.02f
#define INV_R1  0.02f
#define INV_R2  0.03125f
#define INV_R3  0.03125f
#define INV_R4  0.3183098861837907f   // 1/pi
#define MAX_DIST 50.0f

__global__ __launch_bounds__(256) void sim_kernel(
    const float* __restrict__ points,          // [B,N,5]
    const float* __restrict__ ctx,             // [B,M,5]
    const float* __restrict__ dist,            // [B,N,M]
    const unsigned char* __restrict__ imask,   // [B,N,M] bool as u8
    const int* __restrict__ gmd_p,             // scalar
    const float* __restrict__ W1p,             // [5,4] row-major
    const float* __restrict__ b1p,             // [4]
    const float* __restrict__ W2p,             // [4,1]
    const float* __restrict__ b2p,             // [1]
    const float* __restrict__ Wap,             // [5,1]
    const float* __restrict__ bap,             // [1]
    float* __restrict__ out)                   // [B,N]
{
    // 4 waves per block, one row per wave; all 4 rows share batch b
    __shared__ float sctx[MCTX * 5];           // 20 KB: ctx[b] staged

    const int wid  = threadIdx.x >> 6;         // 0..3
    const int lane = threadIdx.x & 63;
    const int row  = blockIdx.x * 4 + wid;     // (b*N + n)
    const int b    = row >> 10;

    // --- cooperative LDS stage of ctx[b]: 5120 floats = 1280 float4 ---
    {
        const float4* __restrict__ src = (const float4*)(ctx + (size_t)b * MCTX * 5);
        float4* dst = (float4*)sctx;
#pragma unroll
        for (int i = 0; i < 5; ++i)
            dst[threadIdx.x + i * 256] = src[threadIdx.x + i * 256];
    }
    __syncthreads();

    // --- tiny weights (uniform addresses -> scalar loads) ---
    float w1[20];
#pragma unroll
    for (int i = 0; i < 20; ++i) w1[i] = W1p[i];
    float b1v[4];
#pragma unroll
    for (int j = 0; j < 4; ++j) b1v[j] = b1p[j];
    float w2[4];
#pragma unroll
    for (int j = 0; j < 4; ++j) w2[j] = W2p[j];
    const float b2v = b2p[0];
    float wa[5];
#pragma unroll
    for (int f = 0; f < 5; ++f) wa[f] = Wap[f];
    const float bav = bap[0];

    // --- this row's point features (wave-uniform) ---
    const float p0 = points[row * 5 + 0];
    const float p1 = points[row * 5 + 1];
    const float p2 = points[row * 5 + 2];
    const float p3 = points[row * 5 + 3];
    const float p4 = points[row * 5 + 4];

    const bool tighten = (MAX_DIST < (float)gmd_p[0]);
    const float* __restrict__ drow         = dist  + (size_t)row * MCTX;
    const unsigned char* __restrict__ mrow = imask + (size_t)row * MCTX;

    // --- preload all 16 dist values + build validity bitmask up front ---
    float d[16];
#pragma unroll
    for (int k = 0; k < 16; ++k) d[k] = drow[lane + 64 * k];
    unsigned valid = 0;
#pragma unroll
    for (int k = 0; k < 16; ++k) {
        bool ok = (mrow[lane + 64 * k] != 0);
        if (tighten) ok = ok && (d[k] <= MAX_DIST);
        valid |= ok ? (1u << k) : 0u;
    }

    // --- branchless fused MLP + softmax accumulation (no max needed:
    //     |score| <= ~2 since features are bounded, exp(score) is safe) ---
    float lsum = 0.0f, asum = 0.0f;
#pragma unroll 4
    for (int k = 0; k < 16; ++k) {
        const int m = lane + 64 * k;
        const float* __restrict__ c = sctx + m * 5;   // stride 5 -> 2 lanes/bank (free)
        float fn0 = fabsf(p0 - c[0]) * INV_R0;
        float fn1 = fabsf(p1 - c[1]) * INV_R1;
        float fn2 = fabsf(p2 - c[2]) * INV_R2;
        float fn3 = fabsf(p3 - c[3]) * INV_R3;
        float f4  = fabsf(p4 - c[4]) * INV_R4;
        f4 = f4 - floorf(f4);                  // remainder(x,1), x>=0
        float fn4 = fminf(f4, 1.0f - f4);      // cyclic wrap distance

        // h = relu(fn @ W1 + b1), W1 row-major [5,4]
        float h0 = fmaxf(0.0f, b1v[0] + fn0*w1[0]  + fn1*w1[4]  + fn2*w1[8]  + fn3*w1[12] + fn4*w1[16]);
        float h1 = fmaxf(0.0f, b1v[1] + fn0*w1[1]  + fn1*w1[5]  + fn2*w1[9]  + fn3*w1[13] + fn4*w1[17]);
        float h2 = fmaxf(0.0f, b1v[2] + fn0*w1[2]  + fn1*w1[6]  + fn2*w1[10] + fn3*w1[14] + fn4*w1[18]);
        float h3 = fmaxf(0.0f, b1v[3] + fn0*w1[3]  + fn1*w1[7]  + fn2*w1[11] + fn3*w1[15] + fn4*w1[19]);
        float z  = b2v + h0*w2[0] + h1*w2[1] + h2*w2[2] + h3*w2[3];
        float energy = 1.0f / (1.0f + __expf(-z));    // sigmoid

        float score = bav + fn0*wa[0] + fn1*wa[1] + fn2*wa[2] + fn3*wa[3] + fn4*wa[4];
        float e = ((valid >> k) & 1u) ? __expf(score) : 0.0f;

        lsum += e;
        asum += e * energy;
    }

    // --- 64-lane butterfly sum of (lsum, asum) ---
#pragma unroll
    for (int off = 1; off < 64; off <<= 1) {
        lsum += __shfl_xor(lsum, off, 64);
        asum += __shfl_xor(asum, off, 64);
    }

    if (lane == 0) {
        out[row] = (lsum > 0.0f) ? (asum / lsum) : 0.0f;   // all-masked -> 0
    }
}

extern "C" void kernel_launch(void* const* d_in, const int* in_sizes, int n_in,
                              void* d_out, int out_size, void* d_ws, size_t ws_size,
                              hipStream_t stream) {
    const float*         points = (const float*)d_in[0];
    // d_in[1] points_mask: unused by reference
    const float*         ctx    = (const float*)d_in[2];
    // d_in[3] context_points_mask: unused by reference
    const float*         dist   = (const float*)d_in[4];
    const unsigned char* imask  = (const unsigned char*)d_in[5];
    const int*           gmd    = (const int*)d_in[6];
    const float*         W1     = (const float*)d_in[7];
    const float*         b1     = (const float*)d_in[8];
    const float*         W2     = (const float*)d_in[9];
    const float*         b2     = (const float*)d_in[10];
    const float*         Wa     = (const float*)d_in[11];
    const float*         ba     = (const float*)d_in[12];
    float*               out    = (float*)d_out;

    dim3 block(256);
    dim3 grid(BN / 4);   // 2048 blocks, 4 waves (rows) each
    sim_kernel<<<grid, block, 0, stream>>>(points, ctx, dist, imask, gmd,
                                           W1, b1, W2, b2, Wa, ba, out);
}

// Round 3
// 16.246 us; speedup vs baseline: 2.2984x; 1.7402x over previous
//
#include <hip/hip_runtime.h>
#include <math.h>

// Problem constants (from reference setup)
#define BATCH   8
#define NPTS    1024
#define MCTX    1024
#define BN      (BATCH * NPTS)     // 8192 rows, one wave each

// FEATURES_RANGE = [50, 50, 32, 32, pi]; feature 4 is cyclic
#define INV_R0  0.02f
#define INV_R1  0.02f
#define INV_R2  0.03125f
#define INV_R3  0.03125f
#define INV_R4  0.3183098861837907f   // 1/pi
#define MAX_DIST 50.0f
#define LOG2E   1.4426950408889634f

__global__ __launch_bounds__(512) void sim_kernel(
    const float* __restrict__ points,          // [B,N,5]
    const float* __restrict__ ctx,             // [B,M,5]
    const float* __restrict__ dist,            // [B,N,M]
    const unsigned char* __restrict__ imask,   // [B,N,M] bool as u8
    const int* __restrict__ gmd_p,             // scalar
    const float* __restrict__ W1p,             // [5,4] row-major
    const float* __restrict__ b1p,             // [4]
    const float* __restrict__ W2p,             // [4,1]
    const float* __restrict__ b2p,             // [1]
    const float* __restrict__ Wap,             // [5,1]
    const float* __restrict__ bap,             // [1]
    float* __restrict__ out)                   // [B,N]
{
    // 8 waves per block, one row per wave; all 8 rows share batch b
    __shared__ float sctx[MCTX * 5];            // 20 KB: ctx[b] staged
    __shared__ unsigned short q[8][MCTX];       // 16 KB: per-wave valid-offset queues

    const int wid  = threadIdx.x >> 6;          // 0..7
    const int lane = threadIdx.x & 63;
    const int row  = blockIdx.x * 8 + wid;      // (b*N + n)
    const int b    = row >> 10;

    // --- cooperative LDS stage of ctx[b]: 5120 floats = 1280 float4 ---
    {
        const float4* __restrict__ src = (const float4*)(ctx + (size_t)b * MCTX * 5);
        float4* dst = (float4*)sctx;
        for (int i = threadIdx.x; i < (MCTX * 5) / 4; i += 512)
            dst[i] = src[i];
    }
    __syncthreads();

    // --- tiny weights (uniform addresses -> scalar loads / SGPRs) ---
    float w1[20];
#pragma unroll
    for (int i = 0; i < 20; ++i) w1[i] = W1p[i];
    float b1v[4];
#pragma unroll
    for (int j = 0; j < 4; ++j) b1v[j] = b1p[j];
    // fold -log2(e) into W2/b2:  sigmoid(z) = 1/(1 + 2^(-z*log2e))
    float w2n[4];
#pragma unroll
    for (int j = 0; j < 4; ++j) w2n[j] = W2p[j] * (-LOG2E);
    const float b2n = b2p[0] * (-LOG2E);
    // fold +log2(e) into Wa/ba:  exp(score) = 2^(score*log2e)
    float wan[5];
#pragma unroll
    for (int f = 0; f < 5; ++f) wan[f] = Wap[f] * LOG2E;
    const float ban = bap[0] * LOG2E;

    // --- this row's point features (wave-uniform values) ---
    const float p0 = points[row * 5 + 0];
    const float p1 = points[row * 5 + 1];
    const float p2 = points[row * 5 + 2];
    const float p3 = points[row * 5 + 3];
    const float p4 = points[row * 5 + 4];

    const bool tighten = (MAX_DIST < (float)gmd_p[0]);
    const float4*        __restrict__ d4 = (const float4*)(dist + (size_t)row * MCTX);
    const unsigned int*  __restrict__ m4 = (const unsigned int*)(imask + (size_t)row * MCTX);

    // --- compaction: enqueue ctx byte-offsets (20*m) of valid pairs ---
    int tot = 0;                                 // wave-uniform running count
#pragma unroll
    for (int j = 0; j < 4; ++j) {
        const float4       dv = d4[lane + 64 * j];
        const unsigned int mv = m4[lane + 64 * j];
        const float dd[4] = { dv.x, dv.y, dv.z, dv.w };
#pragma unroll
        for (int t = 0; t < 4; ++t) {
            bool ok = ((mv >> (8 * t)) & 0xFFu) != 0u;
            if (tighten) ok = ok && (dd[t] <= MAX_DIST);
            unsigned long long bm = __ballot(ok);
            unsigned rank = __builtin_amdgcn_mbcnt_hi(
                                (unsigned)(bm >> 32),
                                __builtin_amdgcn_mbcnt_lo((unsigned)bm, 0u));
            if (ok) {
                const int m = (lane + 64 * j) * 4 + t;
                q[wid][tot + rank] = (unsigned short)(20 * m);   // byte offset into sctx
            }
            tot += (int)__popcll(bm);
        }
    }

    // --- fused MLP + softmax over the ~25%-dense compacted set ---
    float lsum = 0.0f, asum = 0.0f;
    const char* __restrict__ cbase = (const char*)sctx;
#pragma unroll 2
    for (int i = lane; i < tot; i += 64) {
        const int off = (int)q[wid][i];
        const float* __restrict__ c = (const float*)(cbase + off);
        const float c0 = c[0], c1 = c[1], c2 = c[2], c3 = c[3], c4 = c[4];

        float fn0 = fabsf(p0 - c0) * INV_R0;
        float fn1 = fabsf(p1 - c1) * INV_R1;
        float fn2 = fabsf(p2 - c2) * INV_R2;
        float fn3 = fabsf(p3 - c3) * INV_R3;
        float f4  = __builtin_amdgcn_fractf(fabsf(p4 - c4) * INV_R4); // rem(x,1), x>=0
        float fn4 = fminf(f4, 1.0f - f4);       // cyclic wrap distance

        // h = relu(fn @ W1 + b1), W1 row-major [5,4]
        float h0 = fmaxf(0.0f, b1v[0] + fn0*w1[0]  + fn1*w1[4]  + fn2*w1[8]  + fn3*w1[12] + fn4*w1[16]);
        float h1 = fmaxf(0.0f, b1v[1] + fn0*w1[1]  + fn1*w1[5]  + fn2*w1[9]  + fn3*w1[13] + fn4*w1[17]);
        float h2 = fmaxf(0.0f, b1v[2] + fn0*w1[2]  + fn1*w1[6]  + fn2*w1[10] + fn3*w1[14] + fn4*w1[18]);
        float h3 = fmaxf(0.0f, b1v[3] + fn0*w1[3]  + fn1*w1[7]  + fn2*w1[11] + fn3*w1[15] + fn4*w1[19]);

        // zn = -z*log2e ;  energy = sigmoid(z) = rcp(1 + 2^zn)
        float zn = b2n + h0*w2n[0] + h1*w2n[1] + h2*w2n[2] + h3*w2n[3];
        float energy = __builtin_amdgcn_rcpf(1.0f + __builtin_amdgcn_exp2f(zn));

        // e = exp(score) = 2^(score*log2e)   (scores bounded ~[-2,2]: no max needed)
        float sc = ban + fn0*wan[0] + fn1*wan[1] + fn2*wan[2] + fn3*wan[3] + fn4*wan[4];
        float e  = __builtin_amdgcn_exp2f(sc);

        lsum += e;
        asum += e * energy;
    }

    // --- 64-lane butterfly sum of (lsum, asum) ---
#pragma unroll
    for (int off = 1; off < 64; off <<= 1) {
        lsum += __shfl_xor(lsum, off, 64);
        asum += __shfl_xor(asum, off, 64);
    }

    if (lane == 0) {
        out[row] = (lsum > 0.0f) ? (asum / lsum) : 0.0f;   // all-masked -> 0
    }
}

extern "C" void kernel_launch(void* const* d_in, const int* in_sizes, int n_in,
                              void* d_out, int out_size, void* d_ws, size_t ws_size,
                              hipStream_t stream) {
    const float*         points = (const float*)d_in[0];
    // d_in[1] points_mask: unused by reference
    const float*         ctx    = (const float*)d_in[2];
    // d_in[3] context_points_mask: unused by reference
    const float*         dist   = (const float*)d_in[4];
    const unsigned char* imask  = (const unsigned char*)d_in[5];
    const int*           gmd    = (const int*)d_in[6];
    const float*         W1     = (const float*)d_in[7];
    const float*         b1     = (const float*)d_in[8];
    const float*         W2     = (const float*)d_in[9];
    const float*         b2     = (const float*)d_in[10];
    const float*         Wa     = (const float*)d_in[11];
    const float*         ba     = (const float*)d_in[12];
    float*               out    = (float*)d_out;

    dim3 block(512);            // 8 waves, one row each
    dim3 grid(BN / 8);          // 1024 blocks -> 4 blocks/CU, 100% wave occupancy
    sim_kernel<<<grid, block, 0, stream>>>(points, ctx, dist, imask, gmd,
                                           W1, b1, W2, b2, Wa, ba, out);
}